// Round 4
// baseline (19982.135 us; speedup 1.0000x reference)
//
#include <hip/hip_runtime.h>
#include <hip/hip_bf16.h>
#include <stdint.h>

// Problem dims
#define T_  48
#define B_  16
#define H_  16
#define W_  48
#define HW_ 768
#define D_  684
#define N_  256
#define M_  256
#define A_  512

// Workspace layout (float offsets). Same footprint as R3 (proven to fit).
#define OFF_SZ     0u
#define OFF_SR     196608u
#define OFF_SH     393216u
#define OFF_UHZT   589824u    // 9 square 256x256 transposes [k][n]
#define OFF_UHRT   655360u
#define OFF_UHHT   720896u
#define OFF_UHZ2T  786432u
#define OFF_UHR2T  851968u
#define OFF_UHH2T  917504u
#define OFF_WYZT   983040u    // dead after prep -> barrier counters overlay here
#define OFF_WYRT   1048576u
#define OFF_WYHT   1114112u
#define OFF_WAT    1179648u   // [k=256][a=512]
#define OFF_WCZT   1310720u   // [d=684][n=256] x3
#define OFF_UAT    1836032u   // [d=684][a=512]
#define OFF_KCB    2186240u   // K_comb^T bf16 [a=512][k=128] = 32768 floats
#define OFF_G1     2219008u   // gates1 [b][3][256]
#define OFF_G2     2231296u   // gates2 [b][4][256]
#define OFF_H      2247680u   // h state  B*N
#define OFF_H1     2251776u   // h1 state B*N
#define OFF_WAH    2255872u   // Wa*h1 + Ua_b + Uf_b  B*A
#define OFF_CT     2264064u   // ct state B*D
#define OFF_AP     2275008u   // alpha_past B*HW
#define OFF_AUN    2287296u   // per-step e partial sums (atomic) B*HW
#define OFF_UACTX  2299584u   // Ua_ctx bf16 [b][hw][a]; end 5445312

#define OFF_BAR    OFF_WYZT   // barrier counters (2 words), dead weight region

// d_out offsets
#define OUT_H2 0u
#define OUT_CT 196608u
#define OUT_AL 721920u
#define OUT_AP 1311744u

#define NBLK 384

typedef __attribute__((ext_vector_type(8))) short bf16x8;
typedef __attribute__((ext_vector_type(16))) float floatx16;

__device__ __forceinline__ float sigf(float x)  { return 1.f / (1.f + __expf(-x)); }
__device__ __forceinline__ float tanhf_(float x){ float e = __expf(2.f*x); return 1.f - 2.f/(e + 1.f); }
__device__ __forceinline__ float bfval(unsigned short u){ return __uint_as_float(((unsigned)u) << 16); }
__device__ __forceinline__ unsigned short f2bf(float f){
  unsigned int x = __float_as_uint(f);
  return (unsigned short)((x + 0x7fffu + ((x >> 16) & 1u)) >> 16);  // RNE
}

// ---------------- prep: weight transposes + zero alpha_past ----------------
__global__ void k_prep(const float* __restrict__ Uhz, const float* __restrict__ Uhr, const float* __restrict__ Uhh,
                       const float* __restrict__ Uhz2, const float* __restrict__ Uhr2, const float* __restrict__ Uhh2,
                       const float* __restrict__ Wyz, const float* __restrict__ Wyr, const float* __restrict__ Wyh,
                       const float* __restrict__ Wa, const float* __restrict__ Wcz, const float* __restrict__ Wcr,
                       const float* __restrict__ Wch, const float* __restrict__ Ua, float* __restrict__ ws)
{
  int i = blockIdx.x * 256 + threadIdx.x;
  if (i < 589824) {                     // 9 x (256x256) -> [k][n]
    int m = i >> 16, rem = i & 65535, r = rem >> 8, c = rem & 255;
    const float* s;
    switch (m) { case 0: s=Uhz; break; case 1: s=Uhr; break; case 2: s=Uhh; break;
                 case 3: s=Uhz2; break; case 4: s=Uhr2; break; case 5: s=Uhh2; break;
                 case 6: s=Wyz; break; case 7: s=Wyr; break; default: s=Wyh; }
    ws[OFF_UHZT + m*65536 + c*256 + r] = s[rem];
  } else if (i < 720896) {              // Wa [512][256] -> WaT [256][512]
    int j = i - 589824, r = j >> 8, c = j & 255;
    ws[OFF_WAT + c*512 + r] = Wa[j];
  } else if (i < 1246208) {             // Wc* [256][684] -> [684][256]
    int j = i - 720896; int m = j / 175104; int rem = j - m*175104;
    int r = rem / 684, c = rem - r*684;
    const float* s = (m == 0) ? Wcz : (m == 1) ? Wcr : Wch;
    ws[OFF_WCZT + m*175104 + c*256 + r] = s[rem];
  } else if (i < 1596416) {             // Ua [512][684] -> UaT [684][512]
    int j = i - 1246208; int r = j / 684, c = j - r*684;
    ws[OFF_UAT + c*512 + r] = Ua[j];
  } else if (i < 1608704) {             // zero alpha_past
    ws[OFF_AP + (i - 1596416)] = 0.f;
  }
}

// ---------------- K_comb^T bf16 [a=512][k=128] ----------------
__global__ void k_kcomb(const float* __restrict__ Uf, const float* __restrict__ Qw, float* __restrict__ ws)
{
  __shared__ float s_uf[16 * 516];
  int tid = threadIdx.x, a0 = blockIdx.x * 16;
  for (int i = tid; i < 16 * 512; i += 256) { int al = i >> 9, c = i & 511; s_uf[al*516 + c] = Uf[(a0 + al)*512 + c]; }
  __syncthreads();
  int al = tid & 15, kb = tid >> 4;
  unsigned short* kcb = (unsigned short*)(ws + OFF_KCB);
  for (int kk = kb; kk < 128; kk += 16) {
    float acc = 0.f;
    if (kk < 121) {
      #pragma unroll 8
      for (int c = 0; c < 512; ++c) acc += s_uf[al*516 + c] * Qw[c*121 + kk];
    }
    kcb[(size_t)(a0 + al)*128 + kk] = f2bf(acc);
  }
}

// ---------------- embedding projections ----------------
__global__ void k_embproj(const float* __restrict__ emb, const float* __restrict__ bz,
                          const float* __restrict__ br, const float* __restrict__ bh,
                          float* __restrict__ ws)
{
  __shared__ __align__(16) float s_e[256 * 16];
  int tid = threadIdx.x, row0 = blockIdx.x * 16;
  for (int i = tid; i < 4096; i += 256) { int r = i >> 8, m = i & 255; s_e[m*16 + r] = emb[(row0 + r)*256 + m]; }
  __syncthreads();
  int n = tid;
  float az[16], arr[16], ahh[16];
  float vz = bz[n], vr = br[n], vh = bh[n];
  #pragma unroll
  for (int r = 0; r < 16; ++r) { az[r] = vz; arr[r] = vr; ahh[r] = vh; }
  for (int m = 0; m < 256; ++m) {
    float wz = ws[OFF_WYZT + m*256 + n], wr = ws[OFF_WYRT + m*256 + n], wh = ws[OFF_WYHT + m*256 + n];
    #pragma unroll
    for (int r = 0; r < 16; ++r) { float e = s_e[m*16 + r]; az[r] += wz*e; arr[r] += wr*e; ahh[r] += wh*e; }
  }
  #pragma unroll
  for (int r = 0; r < 16; ++r) {
    int ro = (row0 + r)*256 + n;
    ws[OFF_SZ + ro] = az[r]; ws[OFF_SR + ro] = arr[r]; ws[OFF_SH + ro] = ahh[r];
  }
}

// ---------------- Ua_ctx[b][hw][a] bf16 ----------------
__global__ void __launch_bounds__(512) k_uactx(const float* __restrict__ ctx, float* __restrict__ ws)
{
  __shared__ __align__(16) float s_c[684 * 16];
  int tid = threadIdx.x;
  int b = blockIdx.x / 48, chunk = blockIdx.x % 48, hw0 = chunk * 16;
  for (int i = tid; i < 684*16; i += 512) {
    int d = i >> 4, r = i & 15;
    s_c[i] = ctx[((size_t)(b*684 + d))*768 + hw0 + r];
  }
  __syncthreads();
  int a = tid;
  float acc[16];
  #pragma unroll
  for (int r = 0; r < 16; ++r) acc[r] = 0.f;
  const float* uat = ws + OFF_UAT;
  for (int d = 0; d < 684; ++d) {
    float wv = uat[d*512 + a];
    const float4* cp = (const float4*)(s_c + d*16);
    float4 c0 = cp[0], c1 = cp[1], c2 = cp[2], c3 = cp[3];
    acc[0]  += wv*c0.x; acc[1]  += wv*c0.y; acc[2]  += wv*c0.z; acc[3]  += wv*c0.w;
    acc[4]  += wv*c1.x; acc[5]  += wv*c1.y; acc[6]  += wv*c1.z; acc[7]  += wv*c1.w;
    acc[8]  += wv*c2.x; acc[9]  += wv*c2.y; acc[10] += wv*c2.z; acc[11] += wv*c2.w;
    acc[12] += wv*c3.x; acc[13] += wv*c3.y; acc[14] += wv*c3.z; acc[15] += wv*c3.w;
  }
  unsigned short* up = (unsigned short*)(ws + OFF_UACTX);
  #pragma unroll
  for (int r = 0; r < 16; ++r) up[((size_t)(b*768 + hw0 + r))*512 + a] = f2bf(acc[r]);
}

// ---------------- barrier init (runs AFTER k_embproj; overlays dead WYZT) ----
__global__ void k_barinit(float* __restrict__ ws)
{
  if (threadIdx.x < 4) ((unsigned*)(ws + OFF_BAR))[threadIdx.x] = 0u;
}

// ---------------- persistent scan kernel: whole 48-step loop ----------------
struct SMemC { unsigned short sA[64*136]; float sWah[512]; float sVa[512]; };
struct SMemA { float s_h[256]; float s_part[8][32]; };
struct SMemB { float s_h1[256]; float s_part[8][32]; };
struct SMemD { float s_al[768]; float s_red[4]; };
struct SMemE { float s_a[960]; float s_p[16][64]; };
union SMemU { SMemC c; SMemA a; SMemB b; SMemD d; SMemE e; };

__global__ void __launch_bounds__(256, 2) k_scan(
    const float* __restrict__ inits, const float* __restrict__ maskp,
    const float* __restrict__ ctx, const float* __restrict__ cmask,
    const float* __restrict__ va, const float* __restrict__ vab,
    const float* __restrict__ Uab, const float* __restrict__ Ufb,
    const float* __restrict__ bz2, const float* __restrict__ br2, const float* __restrict__ bh2,
    float* out, float* ws)
{
  __shared__ SMemU sm;
  const int tid = threadIdx.x;
  const int blk = blockIdx.x;
  unsigned* bar = (unsigned*)(ws + OFF_BAR);
  unsigned gen = 0;

  auto gbar = [&]() {
    __syncthreads();               // drains this block's vmcnt (compiler-enforced)
    if (tid == 0) {
      __threadfence();             // agent release: publish stores past XCD L2
      unsigned target = gen + 1;
      unsigned t = atomicAdd(&bar[0], 1u) + 1u;
      if (t == target * NBLK) {
        __hip_atomic_store(&bar[1], target, __ATOMIC_RELEASE, __HIP_MEMORY_SCOPE_AGENT);
      } else {
        while (__hip_atomic_load(&bar[1], __ATOMIC_ACQUIRE, __HIP_MEMORY_SCOPE_AGENT) < target)
          __builtin_amdgcn_s_sleep(2);
      }
      __threadfence();             // agent acquire: invalidate stale L1/L2 lines
    }
    __syncthreads();
    gen++;
  };

  const int bA = blk / 24, chA = blk % 24;          // b-major mapping for A/C/D
  const int gA = chA >> 3, n0A = (chA & 7) * 32;

  for (int t = 0; t <= 48; ++t) {
    // ======== Phase A: h2->h combine (+G1 matvec), AUN zero ========
    {
      int n = tid;
      float hv;
      if (t == 0) {
        hv = inits[bA*256 + n];
      } else {
        float h1 = ws[OFF_H1 + bA*256 + n];
        float z2 = sigf(ws[OFF_G2 + (bA*4 + 0)*256 + n] + bz2[n]);
        float r2 = sigf(ws[OFF_G2 + (bA*4 + 1)*256 + n] + br2[n]);
        float h2p = tanhf_(ws[OFF_G2 + (bA*4 + 2)*256 + n] + (ws[OFF_G2 + (bA*4 + 3)*256 + n] + bh2[n]) * r2);
        float h2 = z2*h1 + (1.f - z2)*h2p;
        float m = maskp[(t-1)*16 + bA];
        hv = m*h2 + (1.f - m)*h1;
        if (chA == 0) out[OUT_H2 + (size_t)((t-1)*16 + bA)*256 + n] = hv;
      }
      if (t == 48) break;                            // uniform exit (final combine done)
      sm.a.s_h[n] = hv;
      if (chA == 0) ws[OFF_H + bA*256 + n] = hv;
    }
    if (chA == 0) for (int i = tid; i < 768; i += 256) ws[OFF_AUN + bA*768 + i] = 0.f;
    __syncthreads();
    {
      int nl = tid & 31, kq = tid >> 5;
      const float* Wb = ws + OFF_UHZT + gA*65536;
      float acc = 0.f;
      #pragma unroll 8
      for (int k = kq*32; k < kq*32 + 32; ++k) acc += Wb[k*256 + n0A + nl] * sm.a.s_h[k];
      sm.a.s_part[kq][nl] = acc;
      __syncthreads();
      if (tid < 32) {
        float v = 0.f;
        #pragma unroll
        for (int j = 0; j < 8; ++j) v += sm.a.s_part[j][tid];
        ws[OFF_G1 + (bA*3 + gA)*256 + n0A + tid] = v;
      }
    }
    gbar();

    // ======== Phase B: h1 elementwise + WaH ========
    if (blk < 256) {
      int bB = blk >> 4, ac = blk & 15;
      {
        int n = tid; int ro = (t*16 + bB)*256 + n;
        float h  = ws[OFF_H + bB*256 + n];
        float z1 = sigf(ws[OFF_G1 + (bB*3+0)*256 + n] + ws[OFF_SZ + ro]);
        float r1 = sigf(ws[OFF_G1 + (bB*3+1)*256 + n] + ws[OFF_SR + ro]);
        float h1p = tanhf_(ws[OFF_G1 + (bB*3+2)*256 + n] * r1 + ws[OFF_SH + ro]);
        float m = maskp[t*16 + bB];
        float h1 = m*(z1*h + (1.f - z1)*h1p) + (1.f - m)*h;
        sm.b.s_h1[n] = h1;
        if (ac == 0) ws[OFF_H1 + bB*256 + n] = h1;
      }
      __syncthreads();
      int al = tid & 31, kq = tid >> 5;
      int a0 = ac*32;
      float acc = 0.f;
      #pragma unroll 8
      for (int k = kq*32; k < kq*32 + 32; ++k) acc += ws[OFF_WAT + k*512 + a0 + al] * sm.b.s_h1[k];
      sm.b.s_part[kq][al] = acc;
      __syncthreads();
      if (tid < 32) {
        float v = 0.f;
        #pragma unroll
        for (int j = 0; j < 8; ++j) v += sm.b.s_part[j][tid];
        int a = a0 + tid;
        ws[OFF_WAH + bB*512 + a] = v + Uab[a] + Ufb[a];
      }
    }
    gbar();

    // ======== Phase C: cover MFMA GEMM + tanh + va partial e ========
    {
      int b = bA; int mt = chA >> 1; int nt2 = chA & 1;
      for (int i = tid; i < 512; i += 256) { sm.c.sWah[i] = ws[OFF_WAH + b*512 + i]; sm.c.sVa[i] = va[i]; }
      const float* ap = ws + OFF_AP + b*768;
      for (int idx = tid; idx < 64*128; idx += 256) {
        int r = idx & 63, k = idx >> 6;
        int hw = mt*64 + r; int hh = hw / 48; int wwp = hw - hh*48;
        float v = 0.f;
        if (k < 121) {
          int kh = k / 11, kw = k - kh*11;
          int shh = hh + kh - 5, sww = wwp + kw - 5;
          if (shh >= 0 && shh < 16 && sww >= 0 && sww < 48) v = ap[shh*48 + sww];
        }
        sm.c.sA[r*136 + k] = f2bf(v);
      }
      __syncthreads();
      int lane = tid & 63; int w = tid >> 6; int mw = w >> 1; int nw = w & 1;
      int c5 = lane & 31; int q = lane >> 5;
      bf16x8 af[8];
      {
        int m = mw*32 + c5;
        #pragma unroll
        for (int ks = 0; ks < 8; ++ks)
          af[ks] = *(const bf16x8*)(sm.c.sA + m*136 + ks*16 + q*8);
      }
      const unsigned short* kct = (const unsigned short*)(ws + OFF_KCB);
      const unsigned short* uact = (const unsigned short*)(ws + OFF_UACTX);
      float e_part[16];
      #pragma unroll
      for (int r = 0; r < 16; ++r) e_part[r] = 0.f;

      for (int sp = 0; sp < 2; ++sp) {
        int n_base = nt2*256 + nw*128 + sp*64;
        floatx16 acc[2];
        #pragma unroll
        for (int r = 0; r < 16; ++r) { acc[0][r] = 0.f; acc[1][r] = 0.f; }
        const bf16x8* kb0 = (const bf16x8*)(kct + (size_t)(n_base + c5)*128 + q*8);
        const bf16x8* kb1 = (const bf16x8*)(kct + (size_t)(n_base + 32 + c5)*128 + q*8);
        #pragma unroll
        for (int ks = 0; ks < 8; ++ks) {
          bf16x8 b0 = kb0[ks*2];
          bf16x8 b1 = kb1[ks*2];
          acc[0] = __builtin_amdgcn_mfma_f32_32x32x16_bf16(af[ks], b0, acc[0], 0, 0, 0);
          acc[1] = __builtin_amdgcn_mfma_f32_32x32x16_bf16(af[ks], b1, acc[1], 0, 0, 0);
        }
        #pragma unroll
        for (int half = 0; half < 2; ++half) {
          int col = n_base + half*32 + c5;
          float vav = sm.c.sVa[col], wah = sm.c.sWah[col];
          #pragma unroll
          for (int r = 0; r < 16; ++r) {
            int row32 = (r & 3) + 8*(r >> 2) + 4*q;
            int hw = mt*64 + mw*32 + row32;
            float x = acc[half][r] + wah + bfval(uact[((size_t)(b*768 + hw))*512 + col]);
            e_part[r] += vav * tanhf_(x);
          }
        }
      }
      #pragma unroll
      for (int r = 0; r < 16; ++r) {
        float v = e_part[r];
        v += __shfl_xor(v, 1); v += __shfl_xor(v, 2); v += __shfl_xor(v, 4);
        v += __shfl_xor(v, 8); v += __shfl_xor(v, 16);
        e_part[r] = v;
      }
      if (c5 == 0) {
        #pragma unroll
        for (int r = 0; r < 16; ++r) {
          int row32 = (r & 3) + 8*(r >> 2) + 4*q;
          int hw = mt*64 + mw*32 + row32;
          atomicAdd(&ws[OFF_AUN + b*768 + hw], e_part[r]);
        }
      }
    }
    gbar();

    // ======== Phase D: softmax + AP update + ct ========
    {
      int bD = bA, dc = chA;
      float vb = vab[0];
      float local = 0.f;
      for (int i = tid; i < 768; i += 256) {
        float e = ws[OFF_AUN + bD*768 + i] + vb;
        float un = __expf(e) * cmask[bD*768 + i];
        sm.d.s_al[i] = un; local += un;
      }
      local += __shfl_xor(local, 1); local += __shfl_xor(local, 2); local += __shfl_xor(local, 4);
      local += __shfl_xor(local, 8); local += __shfl_xor(local, 16); local += __shfl_xor(local, 32);
      if ((tid & 63) == 0) sm.d.s_red[tid >> 6] = local;
      __syncthreads();
      float inv = 1.f / (sm.d.s_red[0] + sm.d.s_red[1] + sm.d.s_red[2] + sm.d.s_red[3]);
      if (dc == 0) {
        float* outA = out + OUT_AL + (size_t)(t*16 + bD)*768;
        float* outP = out + OUT_AP + (size_t)(t*16 + bD)*768;
        for (int i = tid; i < 768; i += 256) {
          float av = sm.d.s_al[i] * inv;
          float np = ws[OFF_AP + bD*768 + i] + av;
          ws[OFF_AP + bD*768 + i] = np;
          outA[i] = av; outP[i] = np;
        }
      }
      int dl = tid >> 2, q = tid & 3;
      int d = dc*29 + dl;
      if (dl < 29 && d < 684) {
        const float4* cp  = (const float4*)(ctx + ((size_t)(bD*684 + d))*768 + q*192);
        const float4* ap_ = (const float4*)(sm.d.s_al + q*192);
        float s = 0.f;
        #pragma unroll 8
        for (int i = 0; i < 48; ++i) {
          float4 cv = cp[i]; float4 av = ap_[i];
          s += cv.x*av.x + cv.y*av.y + cv.z*av.z + cv.w*av.w;
        }
        s += __shfl_xor(s, 1); s += __shfl_xor(s, 2);
        s *= inv;
        if (q == 0) {
          ws[OFF_CT + bD*684 + d] = s;
          out[OUT_CT + (size_t)(t*16 + bD)*684 + d] = s;
        }
      }
    }
    gbar();

    // ======== Phase E: gates2 matvecs ========
    if (blk < 256) {
      int b = blk >> 4; int r4 = blk & 15; int g = r4 >> 2; int q4 = r4 & 3;
      for (int i = tid; i < 684; i += 256) sm.e.s_a[i] = ws[OFF_CT + b*684 + i];
      if (tid < 256) sm.e.s_a[684 + tid] = ws[OFF_H1 + b*256 + tid];
      __syncthreads();
      int nq = tid & 15, kq = tid >> 4;
      int n = q4*64 + nq*4;
      float4 acc = {0.f,0.f,0.f,0.f};
      if (g < 2) {
        int cs = 59, k0 = kq*cs, k1 = min(940, k0 + cs);
        int ka = min(k1, 684);
        for (int k = k0; k < ka; ++k) {
          float av = sm.e.s_a[k];
          float4 wv = *(const float4*)(ws + OFF_WCZT + g*175104 + k*256 + n);
          acc.x += wv.x*av; acc.y += wv.y*av; acc.z += wv.z*av; acc.w += wv.w*av;
        }
        for (int k = (k0 > 684 ? k0 : 684); k < k1; ++k) {
          float av = sm.e.s_a[k];
          float4 wv = *(const float4*)(ws + OFF_UHZ2T + g*65536 + (k - 684)*256 + n);
          acc.x += wv.x*av; acc.y += wv.y*av; acc.z += wv.z*av; acc.w += wv.w*av;
        }
      } else if (g == 2) {
        int cs = 43, k0 = kq*cs, k1 = min(684, k0 + cs);
        for (int k = k0; k < k1; ++k) {
          float av = sm.e.s_a[k];
          float4 wv = *(const float4*)(ws + OFF_WCZT + 2*175104 + k*256 + n);
          acc.x += wv.x*av; acc.y += wv.y*av; acc.z += wv.z*av; acc.w += wv.w*av;
        }
      } else {
        int k0 = kq*16, k1 = k0 + 16;
        for (int k = k0; k < k1; ++k) {
          float av = sm.e.s_a[684 + k];
          float4 wv = *(const float4*)(ws + OFF_UHZ2T + 2*65536 + (k)*256 + n);
          acc.x += wv.x*av; acc.y += wv.y*av; acc.z += wv.z*av; acc.w += wv.w*av;
        }
      }
      *(float4*)(&sm.e.s_p[kq][nq*4]) = acc;
      __syncthreads();
      if (tid < 64) {
        float v = 0.f;
        #pragma unroll
        for (int j = 0; j < 16; ++j) v += sm.e.s_p[j][tid];
        ws[OFF_G2 + (b*4 + g)*256 + q4*64 + tid] = v;
      }
    }
    gbar();
  }
}

extern "C" void kernel_launch(void* const* d_in, const int* in_sizes, int n_in,
                              void* d_out, int out_size, void* d_ws, size_t ws_size,
                              hipStream_t stream)
{
  const float* emb   = (const float*)d_in[0];
  const float* maskp = (const float*)d_in[1];
  const float* ctx   = (const float*)d_in[2];
  const float* cmask = (const float*)d_in[3];
  const float* inits = (const float*)d_in[4];
  const float* Ua    = (const float*)d_in[5];
  const float* Uab   = (const float*)d_in[6];
  const float* Wa    = (const float*)d_in[7];
  const float* Qw    = (const float*)d_in[8];
  const float* Uf    = (const float*)d_in[9];
  const float* Ufb   = (const float*)d_in[10];
  const float* va    = (const float*)d_in[11];
  const float* vab   = (const float*)d_in[12];
  const float* Wyz   = (const float*)d_in[13];
  const float* Wyzb  = (const float*)d_in[14];
  const float* Wyr   = (const float*)d_in[15];
  const float* Wyrb  = (const float*)d_in[16];
  const float* Wyh   = (const float*)d_in[17];
  const float* Wyhb  = (const float*)d_in[18];
  const float* Uhz   = (const float*)d_in[19];
  const float* Uhr   = (const float*)d_in[20];
  const float* Uhh   = (const float*)d_in[21];
  const float* Wcz   = (const float*)d_in[22];
  const float* Wcr   = (const float*)d_in[23];
  const float* Wch   = (const float*)d_in[24];
  const float* Uhz2  = (const float*)d_in[25];
  const float* Uhz2b = (const float*)d_in[26];
  const float* Uhr2  = (const float*)d_in[27];
  const float* Uhr2b = (const float*)d_in[28];
  const float* Uhh2  = (const float*)d_in[29];
  const float* Uhh2b = (const float*)d_in[30];
  float* out = (float*)d_out;
  float* ws  = (float*)d_ws;

  k_prep<<<dim3(6284), dim3(256), 0, stream>>>(Uhz, Uhr, Uhh, Uhz2, Uhr2, Uhh2,
                                               Wyz, Wyr, Wyh, Wa, Wcz, Wcr, Wch, Ua, ws);
  k_kcomb<<<dim3(32), dim3(256), 0, stream>>>(Uf, Qw, ws);
  k_embproj<<<dim3(48), dim3(256), 0, stream>>>(emb, Wyzb, Wyrb, Wyhb, ws);
  k_uactx<<<dim3(768), dim3(512), 0, stream>>>(ctx, ws);
  k_barinit<<<dim3(1), dim3(64), 0, stream>>>(ws);
  k_scan<<<dim3(NBLK), dim3(256), 0, stream>>>(inits, maskp, ctx, cmask, va, vab,
                                               Uab, Ufb, Uhz2b, Uhr2b, Uhh2b, out, ws);
  (void)in_sizes; (void)n_in; (void)out_size; (void)ws_size;
}

// Round 5
// 2769.624 us; speedup vs baseline: 7.2147x; 7.2147x over previous
//
#include <hip/hip_runtime.h>
#include <hip/hip_bf16.h>
#include <stdint.h>

// Problem dims
#define T_  48
#define B_  16
#define HW_ 768
#define D_  684
#define N_  256
#define A_  512

// Workspace layout (float offsets). Footprint identical to R3 (proven).
// WYZT/WYRT/WYHT are dead after k_embproj -> reused for per-step partials.
#define OFF_SZ     0u
#define OFF_SR     196608u
#define OFF_SH     393216u
#define OFF_UHZT   589824u    // gates1 weights [k][n] x3
#define OFF_UHZ2T  786432u    // gates2 h-weights [k][n] x3
#define OFF_G2HP   983040u    // (was WYZT/WYRT) Uh2.h1 partials [b][8][3][256] = 98304
#define OFF_WAHP   1114112u   // (was WYHT) Wa.h1 partials [b][8][512] = 65536
#define OFF_WAT    1179648u   // [k=256][a=512]
#define OFF_WCZT   1310720u   // [d=684][n=256] x3
#define OFF_UAT    1836032u   // [d=684][a=512] (dead after uactx)
#define OFF_KCB    2186240u   // K_comb^T bf16 [a=512][k=128] = 32768 floats
#define OFF_G2CT   2219008u   // Wc.ct accum [b][3][256] = 12288 (atomic)
#define OFF_H1     2251776u   // h1 state B*N
#define OFF_AP     2275008u   // alpha_past B*HW
#define OFF_AUN    2287296u   // per-step e partial sums (atomic) B*HW
#define OFF_UACTX  2299584u   // Ua_ctx bf16 [b][hw][a]; end 5445312

// d_out offsets
#define OUT_H2 0u
#define OUT_CT 196608u
#define OUT_AL 721920u
#define OUT_AP 1311744u

typedef __attribute__((ext_vector_type(8))) short bf16x8;
typedef __attribute__((ext_vector_type(16))) float floatx16;

__device__ __forceinline__ float sigf(float x)  { return 1.f / (1.f + __expf(-x)); }
__device__ __forceinline__ float tanhf_(float x){ float e = __expf(2.f*x); return 1.f - 2.f/(e + 1.f); }
__device__ __forceinline__ float bfval(unsigned short u){ return __uint_as_float(((unsigned)u) << 16); }
__device__ __forceinline__ unsigned short f2bf(float f){
  unsigned int x = __float_as_uint(f);
  return (unsigned short)((x + 0x7fffu + ((x >> 16) & 1u)) >> 16);  // RNE
}

// ---------------- prep: weight transposes + zero alpha_past ----------------
__global__ void k_prep(const float* __restrict__ Uhz, const float* __restrict__ Uhr, const float* __restrict__ Uhh,
                       const float* __restrict__ Uhz2, const float* __restrict__ Uhr2, const float* __restrict__ Uhh2,
                       const float* __restrict__ Wyz, const float* __restrict__ Wyr, const float* __restrict__ Wyh,
                       const float* __restrict__ Wa, const float* __restrict__ Wcz, const float* __restrict__ Wcr,
                       const float* __restrict__ Wch, const float* __restrict__ Ua, float* __restrict__ ws)
{
  int i = blockIdx.x * 256 + threadIdx.x;
  if (i < 589824) {                     // 9 x (256x256) -> [k][n]; first 6 are Uh*, last 3 Wy* (to G2HP region, prep-only)
    int m = i >> 16, rem = i & 65535, r = rem >> 8, c = rem & 255;
    const float* s;
    unsigned dst;
    switch (m) { case 0: s=Uhz;  dst=OFF_UHZT;            break;
                 case 1: s=Uhr;  dst=OFF_UHZT+65536u;     break;
                 case 2: s=Uhh;  dst=OFF_UHZT+131072u;    break;
                 case 3: s=Uhz2; dst=OFF_UHZ2T;           break;
                 case 4: s=Uhr2; dst=OFF_UHZ2T+65536u;    break;
                 case 5: s=Uhh2; dst=OFF_UHZ2T+131072u;   break;
                 case 6: s=Wyz;  dst=OFF_G2HP;            break;  // WYZT (dead after embproj)
                 case 7: s=Wyr;  dst=OFF_G2HP+65536u;     break;  // WYRT
                 default: s=Wyh; dst=OFF_WAHP;            break;} // WYHT
    ws[dst + c*256 + r] = s[rem];
  } else if (i < 720896) {              // Wa [512][256] -> WaT [256][512]
    int j = i - 589824, r = j >> 8, c = j & 255;
    ws[OFF_WAT + c*512 + r] = Wa[j];
  } else if (i < 1246208) {             // Wc* [256][684] -> [684][256]
    int j = i - 720896; int m = j / 175104; int rem = j - m*175104;
    int r = rem / 684, c = rem - r*684;
    const float* s = (m == 0) ? Wcz : (m == 1) ? Wcr : Wch;
    ws[OFF_WCZT + m*175104 + c*256 + r] = s[rem];
  } else if (i < 1596416) {             // Ua [512][684] -> UaT [684][512]
    int j = i - 1246208; int r = j / 684, c = j - r*684;
    ws[OFF_UAT + c*512 + r] = Ua[j];
  } else if (i < 1608704) {             // zero alpha_past
    ws[OFF_AP + (i - 1596416)] = 0.f;
  }
}

// ---------------- K_comb^T bf16 [a=512][k=128] ----------------
__global__ void k_kcomb(const float* __restrict__ Uf, const float* __restrict__ Qw, float* __restrict__ ws)
{
  __shared__ float s_uf[16 * 516];
  int tid = threadIdx.x, a0 = blockIdx.x * 16;
  for (int i = tid; i < 16 * 512; i += 256) { int al = i >> 9, c = i & 511; s_uf[al*516 + c] = Uf[(a0 + al)*512 + c]; }
  __syncthreads();
  int al = tid & 15, kb = tid >> 4;
  unsigned short* kcb = (unsigned short*)(ws + OFF_KCB);
  for (int kk = kb; kk < 128; kk += 16) {
    float acc = 0.f;
    if (kk < 121) {
      #pragma unroll 8
      for (int c = 0; c < 512; ++c) acc += s_uf[al*516 + c] * Qw[c*121 + kk];
    }
    kcb[(size_t)(a0 + al)*128 + kk] = f2bf(acc);
  }
}

// ---------------- embedding projections (consumes transposed Wy* from partial regions) ----------------
__global__ void k_embproj(const float* __restrict__ emb, const float* __restrict__ bz,
                          const float* __restrict__ br, const float* __restrict__ bh,
                          float* __restrict__ ws)
{
  __shared__ __align__(16) float s_e[256 * 16];
  int tid = threadIdx.x, row0 = blockIdx.x * 16;
  for (int i = tid; i < 4096; i += 256) { int r = i >> 8, m = i & 255; s_e[m*16 + r] = emb[(row0 + r)*256 + m]; }
  __syncthreads();
  int n = tid;
  float az[16], arr[16], ahh[16];
  float vz = bz[n], vr = br[n], vh = bh[n];
  #pragma unroll
  for (int r = 0; r < 16; ++r) { az[r] = vz; arr[r] = vr; ahh[r] = vh; }
  for (int m = 0; m < 256; ++m) {
    float wz = ws[OFF_G2HP + m*256 + n];            // WYZT
    float wr = ws[OFF_G2HP + 65536u + m*256 + n];   // WYRT
    float wh = ws[OFF_WAHP + m*256 + n];            // WYHT
    #pragma unroll
    for (int r = 0; r < 16; ++r) { float e = s_e[m*16 + r]; az[r] += wz*e; arr[r] += wr*e; ahh[r] += wh*e; }
  }
  #pragma unroll
  for (int r = 0; r < 16; ++r) {
    int ro = (row0 + r)*256 + n;
    ws[OFF_SZ + ro] = az[r]; ws[OFF_SR + ro] = arr[r]; ws[OFF_SH + ro] = ahh[r];
  }
}

// ---------------- Ua_ctx[b][hw][a] bf16 ----------------
__global__ void __launch_bounds__(512) k_uactx(const float* __restrict__ ctx, float* __restrict__ ws)
{
  __shared__ __align__(16) float s_c[684 * 16];
  int tid = threadIdx.x;
  int b = blockIdx.x / 48, chunk = blockIdx.x % 48, hw0 = chunk * 16;
  for (int i = tid; i < 684*16; i += 512) {
    int d = i >> 4, r = i & 15;
    s_c[i] = ctx[((size_t)(b*684 + d))*768 + hw0 + r];
  }
  __syncthreads();
  int a = tid;
  float acc[16];
  #pragma unroll
  for (int r = 0; r < 16; ++r) acc[r] = 0.f;
  const float* uat = ws + OFF_UAT;
  for (int d = 0; d < 684; ++d) {
    float wv = uat[d*512 + a];
    const float4* cp = (const float4*)(s_c + d*16);
    float4 c0 = cp[0], c1 = cp[1], c2 = cp[2], c3 = cp[3];
    acc[0]  += wv*c0.x; acc[1]  += wv*c0.y; acc[2]  += wv*c0.z; acc[3]  += wv*c0.w;
    acc[4]  += wv*c1.x; acc[5]  += wv*c1.y; acc[6]  += wv*c1.z; acc[7]  += wv*c1.w;
    acc[8]  += wv*c2.x; acc[9]  += wv*c2.y; acc[10] += wv*c2.z; acc[11] += wv*c2.w;
    acc[12] += wv*c3.x; acc[13] += wv*c3.y; acc[14] += wv*c3.z; acc[15] += wv*c3.w;
  }
  unsigned short* up = (unsigned short*)(ws + OFF_UACTX);
  #pragma unroll
  for (int r = 0; r < 16; ++r) up[((size_t)(b*768 + hw0 + r))*512 + a] = f2bf(acc[r]);
}

// ---------------- K1: h2->h combine + gates1 chunk + h1 chunk + k-partials ----------------
// grid 128 = b(16) x q(8); q owns n-cols/k-rows [q*32, q*32+32)
__global__ void __launch_bounds__(256) k_step1(int t, const float* __restrict__ inits, const float* __restrict__ maskp,
                                               const float* __restrict__ bz2, const float* __restrict__ br2,
                                               const float* __restrict__ bh2,
                                               float* __restrict__ out, float* __restrict__ ws)
{
  __shared__ float s_h[256];
  __shared__ float s_part[3][8][32];
  __shared__ float s_h1[32];
  int tid = threadIdx.x;
  int b = blockIdx.x >> 3, q = blockIdx.x & 7;
  // ---- h combine (redundant per q; cheap) ----
  {
    int n = tid;
    float hv;
    if (t == 0) {
      hv = inits[b*256 + n];
    } else {
      float h1v = ws[OFF_H1 + b*256 + n];
      float gz = ws[OFF_G2CT + (b*3 + 0)*256 + n];
      float gr = ws[OFF_G2CT + (b*3 + 1)*256 + n];
      float gc = ws[OFF_G2CT + (b*3 + 2)*256 + n];
      float gu = 0.f;
      #pragma unroll
      for (int qq = 0; qq < 8; ++qq) {
        gz += ws[OFF_G2HP + (size_t)((b*8 + qq)*3 + 0)*256 + n];
        gr += ws[OFF_G2HP + (size_t)((b*8 + qq)*3 + 1)*256 + n];
        gu += ws[OFF_G2HP + (size_t)((b*8 + qq)*3 + 2)*256 + n];
      }
      float z2 = sigf(gz + bz2[n]);
      float r2 = sigf(gr + br2[n]);
      float h2p = tanhf_(gc + (gu + bh2[n]) * r2);
      float h2 = z2*h1v + (1.f - z2)*h2p;
      float m = maskp[(t-1)*16 + b];
      hv = m*h2 + (1.f - m)*h1v;
      if (q == 0) out[OUT_H2 + (size_t)((t-1)*16 + b)*256 + n] = hv;
    }
    s_h[n] = hv;
  }
  if (q == 0) for (int i = tid; i < 768; i += 256) ws[OFF_AUN + b*768 + i] = 0.f;
  __syncthreads();
  // ---- gates1 for cols q*32..q*32+31 ----
  {
    int nl = tid & 31, kq = tid >> 5;   // kq 0..7, 32 k each
    int col = q*32 + nl;
    const float* Wz = ws + OFF_UHZT;
    const float* Wr = ws + OFF_UHZT + 65536u;
    const float* Wh = ws + OFF_UHZT + 131072u;
    float a0 = 0.f, a1 = 0.f, a2 = 0.f;
    #pragma unroll 8
    for (int k = kq*32; k < kq*32 + 32; ++k) {
      float hk = s_h[k];
      a0 += Wz[k*256 + col]*hk; a1 += Wr[k*256 + col]*hk; a2 += Wh[k*256 + col]*hk;
    }
    s_part[0][kq][nl] = a0; s_part[1][kq][nl] = a1; s_part[2][kq][nl] = a2;
  }
  __syncthreads();
  if (tid < 32) {
    float g0 = 0.f, g1 = 0.f, g2 = 0.f;
    #pragma unroll
    for (int j = 0; j < 8; ++j) { g0 += s_part[0][j][tid]; g1 += s_part[1][j][tid]; g2 += s_part[2][j][tid]; }
    int col = q*32 + tid;
    int ro = (t*16 + b)*256 + col;
    float z1 = sigf(g0 + ws[OFF_SZ + ro]);
    float r1 = sigf(g1 + ws[OFF_SR + ro]);
    float h1p = tanhf_(g2 * r1 + ws[OFF_SH + ro]);
    float m = maskp[t*16 + b];
    float h = s_h[col];
    float h1 = m*(z1*h + (1.f - z1)*h1p) + (1.f - m)*h;
    s_h1[tid] = h1;
    ws[OFF_H1 + b*256 + col] = h1;
  }
  __syncthreads();
  // ---- WaHp over own 32 k's ----
  {
    float acc0 = 0.f, acc1 = 0.f;
    #pragma unroll 8
    for (int j = 0; j < 32; ++j) {
      float h1j = s_h1[j];
      acc0 += ws[OFF_WAT + (q*32 + j)*512 + tid]       * h1j;
      acc1 += ws[OFF_WAT + (q*32 + j)*512 + tid + 256] * h1j;
    }
    ws[OFF_WAHP + (size_t)(b*8 + q)*512 + tid]       = acc0;
    ws[OFF_WAHP + (size_t)(b*8 + q)*512 + tid + 256] = acc1;
  }
  // ---- G2Hp (Uh2 . h1 partials) over own 32 k's ----
  #pragma unroll
  for (int g = 0; g < 3; ++g) {
    const float* Wb = ws + OFF_UHZ2T + g*65536u;
    float acc = 0.f;
    #pragma unroll 8
    for (int j = 0; j < 32; ++j) acc += Wb[(q*32 + j)*256 + tid] * s_h1[j];
    ws[OFF_G2HP + (size_t)((b*8 + q)*3 + g)*256 + tid] = acc;
  }
}

// ---------------- K2: cover MFMA GEMM + tanh + va partial e (+G2CT zero) ----------------
// grid 384 = b(16) x mt(12) x nt2(2); block 256 = 4 waves
__global__ void __launch_bounds__(256) k_cover(const float* __restrict__ va,
                                               const float* __restrict__ Uab, const float* __restrict__ Ufb,
                                               float* __restrict__ ws)
{
  __shared__ unsigned short sA[64 * 136];
  __shared__ float sWah[512];
  __shared__ float sVa[512];
  int tid = threadIdx.x;
  int blk = blockIdx.x;
  int b = blk / 24; int chA = blk % 24; int mt = chA >> 1; int nt2 = chA & 1;
  for (int i = tid; i < 512; i += 256) {
    float v = Uab[i] + Ufb[i];
    #pragma unroll
    for (int qq = 0; qq < 8; ++qq) v += ws[OFF_WAHP + (size_t)(b*8 + qq)*512 + i];
    sWah[i] = v; sVa[i] = va[i];
  }
  if (chA == 0) for (int i = tid; i < 768; i += 256) ws[OFF_G2CT + b*768 + i] = 0.f;
  const float* ap = ws + OFF_AP + b*768;
  for (int idx = tid; idx < 64*128; idx += 256) {
    int r = idx & 63, k = idx >> 6;
    int hw = mt*64 + r; int hh = hw / 48; int wwp = hw - hh*48;
    float v = 0.f;
    if (k < 121) {
      int kh = k / 11, kw = k - kh*11;
      int shh = hh + kh - 5, sww = wwp + kw - 5;
      if (shh >= 0 && shh < 16 && sww >= 0 && sww < 48) v = ap[shh*48 + sww];
    }
    sA[r*136 + k] = f2bf(v);
  }
  __syncthreads();
  int lane = tid & 63; int w = tid >> 6; int mw = w >> 1; int nw = w & 1;
  int c5 = lane & 31; int q = lane >> 5;
  bf16x8 af[8];
  {
    int m = mw*32 + c5;
    #pragma unroll
    for (int ks = 0; ks < 8; ++ks)
      af[ks] = *(const bf16x8*)(sA + m*136 + ks*16 + q*8);
  }
  const unsigned short* kct = (const unsigned short*)(ws + OFF_KCB);
  const unsigned short* uact = (const unsigned short*)(ws + OFF_UACTX);
  float e_part[16];
  #pragma unroll
  for (int r = 0; r < 16; ++r) e_part[r] = 0.f;

  for (int sp = 0; sp < 2; ++sp) {
    int n_base = nt2*256 + nw*128 + sp*64;
    floatx16 acc[2];
    #pragma unroll
    for (int r = 0; r < 16; ++r) { acc[0][r] = 0.f; acc[1][r] = 0.f; }
    const bf16x8* kb0 = (const bf16x8*)(kct + (size_t)(n_base + c5)*128 + q*8);
    const bf16x8* kb1 = (const bf16x8*)(kct + (size_t)(n_base + 32 + c5)*128 + q*8);
    #pragma unroll
    for (int ks = 0; ks < 8; ++ks) {
      bf16x8 b0 = kb0[ks*2];
      bf16x8 b1 = kb1[ks*2];
      acc[0] = __builtin_amdgcn_mfma_f32_32x32x16_bf16(af[ks], b0, acc[0], 0, 0, 0);
      acc[1] = __builtin_amdgcn_mfma_f32_32x32x16_bf16(af[ks], b1, acc[1], 0, 0, 0);
    }
    #pragma unroll
    for (int half = 0; half < 2; ++half) {
      int col = n_base + half*32 + c5;
      float vav = sVa[col], wah = sWah[col];
      #pragma unroll
      for (int r = 0; r < 16; ++r) {
        int row32 = (r & 3) + 8*(r >> 2) + 4*q;
        int hw = mt*64 + mw*32 + row32;
        float x = acc[half][r] + wah + bfval(uact[((size_t)(b*768 + hw))*512 + col]);
        e_part[r] += vav * tanhf_(x);
      }
    }
  }
  #pragma unroll
  for (int r = 0; r < 16; ++r) {
    float v = e_part[r];
    v += __shfl_xor(v, 1); v += __shfl_xor(v, 2); v += __shfl_xor(v, 4);
    v += __shfl_xor(v, 8); v += __shfl_xor(v, 16);
    e_part[r] = v;
  }
  if (c5 == 0) {
    #pragma unroll
    for (int r = 0; r < 16; ++r) {
      int row32 = (r & 3) + 8*(r >> 2) + 4*q;
      int hw = mt*64 + mw*32 + row32;
      atomicAdd(&ws[OFF_AUN + b*768 + hw], e_part[r]);
    }
  }
}

// ---------------- K3: softmax + AP + ct chunk + Wc.ct partials into G2CT ----------------
// grid 352 = b(16) x dc(22); dc owns d-rows [dc*32, dc*32+32)
__global__ void __launch_bounds__(256) k_alpha(int t, const float* __restrict__ ctx, const float* __restrict__ cmask,
                                               const float* __restrict__ vab,
                                               float* __restrict__ out, float* __restrict__ ws)
{
  __shared__ __align__(16) float s_al[768];
  __shared__ float s_red[4];
  __shared__ float s_ct[32];
  int tid = threadIdx.x;
  int b = blockIdx.x / 22, dc = blockIdx.x % 22;
  float vb = vab[0];
  float local = 0.f;
  for (int i = tid; i < 768; i += 256) {
    float e = ws[OFF_AUN + b*768 + i] + vb;
    float un = __expf(e) * cmask[b*768 + i];
    s_al[i] = un; local += un;
  }
  local += __shfl_xor(local, 1); local += __shfl_xor(local, 2); local += __shfl_xor(local, 4);
  local += __shfl_xor(local, 8); local += __shfl_xor(local, 16); local += __shfl_xor(local, 32);
  if ((tid & 63) == 0) s_red[tid >> 6] = local;
  __syncthreads();
  float inv = 1.f / (s_red[0] + s_red[1] + s_red[2] + s_red[3]);
  if (dc == 0) {
    float* outA = out + OUT_AL + (size_t)(t*16 + b)*768;
    float* outP = out + OUT_AP + (size_t)(t*16 + b)*768;
    for (int i = tid; i < 768; i += 256) {
      float av = s_al[i] * inv;
      float np = ws[OFF_AP + b*768 + i] + av;
      ws[OFF_AP + b*768 + i] = np;
      outA[i] = av; outP[i] = np;
    }
  }
  // ct for 32 d-rows: 8 lanes per row, interleaved float4
  {
    int dl = tid >> 3, qq = tid & 7;
    int d = dc*32 + dl;
    if (d < 684) {
      const float4* cp  = (const float4*)(ctx + ((size_t)(b*684 + d))*768);
      const float4* alp = (const float4*)s_al;
      float s = 0.f;
      #pragma unroll 8
      for (int i = 0; i < 24; ++i) {
        float4 cv = cp[i*8 + qq]; float4 av = alp[i*8 + qq];
        s += cv.x*av.x + cv.y*av.y + cv.z*av.z + cv.w*av.w;
      }
      s += __shfl_xor(s, 1); s += __shfl_xor(s, 2); s += __shfl_xor(s, 4);
      s *= inv;
      if (qq == 0) {
        out[OUT_CT + (size_t)(t*16 + b)*684 + d] = s;
        s_ct[dl] = s;
      }
    } else if (qq == 0) {
      s_ct[dl] = 0.f;
    }
  }
  __syncthreads();
  // Wc . ct partials over this d-chunk -> atomic accumulate into G2CT
  {
    int d0 = dc*32;
    int jm = 684 - d0; if (jm > 32) jm = 32;
    #pragma unroll
    for (int g = 0; g < 3; ++g) {
      const float* Wb = ws + OFF_WCZT + g*175104u;
      float acc = 0.f;
      for (int j = 0; j < jm; ++j) acc += Wb[(d0 + j)*256 + tid] * s_ct[j];
      atomicAdd(&ws[OFF_G2CT + (size_t)(b*3 + g)*256 + tid], acc);
    }
  }
}

// ---------------- final combine for t=47 ----------------
__global__ void k_final(const float* __restrict__ maskp, const float* __restrict__ bz2,
                        const float* __restrict__ br2, const float* __restrict__ bh2,
                        float* __restrict__ out, float* __restrict__ ws)
{
  int b = blockIdx.x, n = threadIdx.x;
  float h1v = ws[OFF_H1 + b*256 + n];
  float gz = ws[OFF_G2CT + (b*3 + 0)*256 + n];
  float gr = ws[OFF_G2CT + (b*3 + 1)*256 + n];
  float gc = ws[OFF_G2CT + (b*3 + 2)*256 + n];
  float gu = 0.f;
  #pragma unroll
  for (int qq = 0; qq < 8; ++qq) {
    gz += ws[OFF_G2HP + (size_t)((b*8 + qq)*3 + 0)*256 + n];
    gr += ws[OFF_G2HP + (size_t)((b*8 + qq)*3 + 1)*256 + n];
    gu += ws[OFF_G2HP + (size_t)((b*8 + qq)*3 + 2)*256 + n];
  }
  float z2 = sigf(gz + bz2[n]);
  float r2 = sigf(gr + br2[n]);
  float h2p = tanhf_(gc + (gu + bh2[n]) * r2);
  float h2 = z2*h1v + (1.f - z2)*h2p;
  float m = maskp[47*16 + b];
  out[OUT_H2 + (size_t)(47*16 + b)*256 + n] = m*h2 + (1.f - m)*h1v;
}

extern "C" void kernel_launch(void* const* d_in, const int* in_sizes, int n_in,
                              void* d_out, int out_size, void* d_ws, size_t ws_size,
                              hipStream_t stream)
{
  const float* emb   = (const float*)d_in[0];
  const float* maskp = (const float*)d_in[1];
  const float* ctx   = (const float*)d_in[2];
  const float* cmask = (const float*)d_in[3];
  const float* inits = (const float*)d_in[4];
  const float* Ua    = (const float*)d_in[5];
  const float* Uab   = (const float*)d_in[6];
  const float* Wa    = (const float*)d_in[7];
  const float* Qw    = (const float*)d_in[8];
  const float* Uf    = (const float*)d_in[9];
  const float* Ufb   = (const float*)d_in[10];
  const float* va    = (const float*)d_in[11];
  const float* vab   = (const float*)d_in[12];
  const float* Wyz   = (const float*)d_in[13];
  const float* Wyzb  = (const float*)d_in[14];
  const float* Wyr   = (const float*)d_in[15];
  const float* Wyrb  = (const float*)d_in[16];
  const float* Wyh   = (const float*)d_in[17];
  const float* Wyhb  = (const float*)d_in[18];
  const float* Uhz   = (const float*)d_in[19];
  const float* Uhr   = (const float*)d_in[20];
  const float* Uhh   = (const float*)d_in[21];
  const float* Wcz   = (const float*)d_in[22];
  const float* Wcr   = (const float*)d_in[23];
  const float* Wch   = (const float*)d_in[24];
  const float* Uhz2  = (const float*)d_in[25];
  const float* Uhz2b = (const float*)d_in[26];
  const float* Uhr2  = (const float*)d_in[27];
  const float* Uhr2b = (const float*)d_in[28];
  const float* Uhh2  = (const float*)d_in[29];
  const float* Uhh2b = (const float*)d_in[30];
  float* out = (float*)d_out;
  float* ws  = (float*)d_ws;

  k_prep<<<dim3(6284), dim3(256), 0, stream>>>(Uhz, Uhr, Uhh, Uhz2, Uhr2, Uhh2,
                                               Wyz, Wyr, Wyh, Wa, Wcz, Wcr, Wch, Ua, ws);
  k_kcomb<<<dim3(32), dim3(256), 0, stream>>>(Uf, Qw, ws);
  k_embproj<<<dim3(48), dim3(256), 0, stream>>>(emb, Wyzb, Wyrb, Wyhb, ws);
  k_uactx<<<dim3(768), dim3(512), 0, stream>>>(ctx, ws);

  for (int t = 0; t < 48; ++t) {
    k_step1<<<dim3(128), dim3(256), 0, stream>>>(t, inits, maskp, Uhz2b, Uhr2b, Uhh2b, out, ws);
    k_cover<<<dim3(384), dim3(256), 0, stream>>>(va, Uab, Ufb, ws);
    k_alpha<<<dim3(352), dim3(256), 0, stream>>>(t, ctx, cmask, vab, out, ws);
  }
  k_final<<<dim3(16), dim3(256), 0, stream>>>(maskp, Uhz2b, Uhr2b, Uhh2b, out, ws);
  (void)in_sizes; (void)n_in; (void)out_size; (void)ws_size;
}